// Round 1
// baseline (3767.845 us; speedup 1.0000x reference)
//
#include <hip/hip_runtime.h>
#include <hip/hip_bf16.h>

// RBF kernel matrix: out[i][j] = exp(-gamma * ||x_i - y_j||^2)
// computed as exp(-gamma * max(x2[i] + y2[j] - 2*x.y, 0)).
//
// Round 1: fp32 register-tiled GEMM (no fp32 MFMA exists on CDNA4).
// 128x128 tile, 256 threads, 8x8 micro-tile, K=64 staged in 2 phases of 32
// (LDS ~34 KB -> ~4 blocks/CU). Tiles stored transposed [k][i] with +1 pad
// (<=2-way LDS write conflicts = free). Norms folded in-block; fused exp
// epilogue with coalesced float4 stores.

#define BM 128
#define BN 128
#define BK 32
#define DD 64
#define LDT (BM + 1)   // 129: padded leading dim for transposed tiles

__global__ __launch_bounds__(256, 4)
void rbf_tiled_f32(const float* __restrict__ X, const float* __restrict__ Y,
                   const float* __restrict__ gptr, float* __restrict__ Out,
                   int n, int m) {
  __shared__ float Xs[BK][LDT];
  __shared__ float Ys[BK][LDT];
  __shared__ float xsq[BM];
  __shared__ float ysq[BN];

  const int tid = threadIdx.x;          // 0..255
  const long i0 = (long)blockIdx.y * BM;
  const long j0 = (long)blockIdx.x * BN;
  const int tx = tid & 15;              // 0..15 -> output cols
  const int ty = tid >> 4;              // 0..15 -> output rows

  float acc[8][8];
#pragma unroll
  for (int i = 0; i < 8; ++i)
#pragma unroll
    for (int j = 0; j < 8; ++j) acc[i][j] = 0.f;

#pragma unroll
  for (int ph = 0; ph < 2; ++ph) {
    // ---- stage: X[i0..i0+BM)[ph*BK..+BK) -> Xs[k][i] (transposed), same for Y
    {
      const float4* Xg = (const float4*)(X + i0 * DD + ph * BK);
      const float4* Yg = (const float4*)(Y + j0 * DD + ph * BK);
      // per row: BK floats = 8 float4; global row stride = DD/4 = 16 float4
#pragma unroll
      for (int it = 0; it < 4; ++it) {
        int e = it * 256 + tid;        // 0..1023
        int row = e >> 3;              // 0..127
        int c4 = e & 7;                // 0..7
        float4 v = Xg[row * (DD / 4) + c4];
        Xs[c4 * 4 + 0][row] = v.x;
        Xs[c4 * 4 + 1][row] = v.y;
        Xs[c4 * 4 + 2][row] = v.z;
        Xs[c4 * 4 + 3][row] = v.w;
        float4 w = Yg[row * (DD / 4) + c4];
        Ys[c4 * 4 + 0][row] = w.x;
        Ys[c4 * 4 + 1][row] = w.y;
        Ys[c4 * 4 + 2][row] = w.z;
        Ys[c4 * 4 + 3][row] = w.w;
      }
    }
    __syncthreads();

    // ---- partial squared norms (read-only on tiles; no sync needed vs compute)
    if (tid < BM) {
      float s = (ph == 0) ? 0.f : xsq[tid];
#pragma unroll
      for (int k = 0; k < BK; ++k) { float v = Xs[k][tid]; s = fmaf(v, v, s); }
      xsq[tid] = s;
    } else {
      int c = tid - BM;
      float s = (ph == 0) ? 0.f : ysq[c];
#pragma unroll
      for (int k = 0; k < BK; ++k) { float v = Ys[k][c]; s = fmaf(v, v, s); }
      ysq[c] = s;
    }

    // ---- compute: 8x8 per-thread micro-tile over this K-phase
#pragma unroll
    for (int k = 0; k < BK; ++k) {
      float4 a0 = *(const float4*)&Xs[k][ty * 4];
      float4 a1 = *(const float4*)&Xs[k][64 + ty * 4];
      float4 b0 = *(const float4*)&Ys[k][tx * 4];
      float4 b1 = *(const float4*)&Ys[k][64 + tx * 4];
      float a[8] = {a0.x, a0.y, a0.z, a0.w, a1.x, a1.y, a1.z, a1.w};
      float b[8] = {b0.x, b0.y, b0.z, b0.w, b1.x, b1.y, b1.z, b1.w};
#pragma unroll
      for (int i = 0; i < 8; ++i)
#pragma unroll
        for (int j = 0; j < 8; ++j)
          acc[i][j] = fmaf(a[i], b[j], acc[i][j]);
    }
    __syncthreads();   // guards re-staging (ph 0) / xsq completeness (ph 1)
  }

  // ---- epilogue: exp(-g * max(x2 + y2 - 2xy, 0)), coalesced float4 stores
  const float g = *gptr;
#pragma unroll
  for (int ii = 0; ii < 8; ++ii) {
    const int r = (ii < 4) ? (ty * 4 + ii) : (64 + ty * 4 + (ii - 4));
    const float xr = xsq[r];
    float* op = Out + (i0 + r) * (long)m + j0;
    float o0[4], o1[4];
#pragma unroll
    for (int j = 0; j < 4; ++j) {
      float d0 = fmaxf(xr + ysq[tx * 4 + j]      - 2.f * acc[ii][j],     0.f);
      float d1 = fmaxf(xr + ysq[64 + tx * 4 + j] - 2.f * acc[ii][j + 4], 0.f);
      o0[j] = __expf(-g * d0);
      o1[j] = __expf(-g * d1);
    }
    *(float4*)(op + tx * 4)      = *(float4*)o0;
    *(float4*)(op + 64 + tx * 4) = *(float4*)o1;
  }
}

extern "C" void kernel_launch(void* const* d_in, const int* in_sizes, int n_in,
                              void* d_out, int out_size, void* d_ws, size_t ws_size,
                              hipStream_t stream) {
  const float* x = (const float*)d_in[0];
  const float* y = (const float*)d_in[1];
  const float* g = (const float*)d_in[2];
  float* out = (float*)d_out;

  const int n = in_sizes[0] / DD;   // 8192
  const int m = in_sizes[1] / DD;   // 8192

  dim3 grid(m / BN, n / BM);        // 64 x 64 = 4096 blocks
  rbf_tiled_f32<<<grid, 256, 0, stream>>>(x, y, g, out, n, m);
}

// Round 2
// 61.455 us; speedup vs baseline: 61.3105x; 61.3105x over previous
//
#include <hip/hip_runtime.h>
#include <hip/hip_bf16.h>

// RBF kernel matrix: out[i][j] = exp(-gamma * max(x2[i] + y2[j] - 2*x.y, 0))
//
// Round 2: bf16 MFMA with hi/lo split (x = hi + lo; keep hi*hi + lo*hi + hi*lo,
// drop lo*lo ~ 2^-18 relative -> ~1e-21 abs output error, under 1.5e-20 thresh).
// Exact fp32 row norms from a tiny prep kernel into d_ws.
//
// GEMM kernel: 128x128 tile, 4 waves (2x2), per-wave 64x64 = 4x4 frags of
// mfma_f32_16x16x32_bf16. Whole K=64 staged once into LDS (no global k-loop):
// 4 tiles (Xhi,Xlo,Yhi,Ylo) of 128x64 bf16 = exactly 64 KB, XOR-swizzled
// (byte ^= (row&7)<<4) so ds_read_b128 frag loads are <=2-way (free).
// A/B use the same (lane,elem)->k mapping, so the result is invariant to the
// HW's internal k-grouping. C/D layout: col=lane&15, row=(lane>>4)*4+reg.
// Fused exp epilogue. Write-bound: 268 MB out -> ~43 us floor.

#define DD 64
#define BM 128
#define BN 128

typedef __attribute__((ext_vector_type(8))) short short8;
typedef __attribute__((ext_vector_type(4))) float f32x4;

__device__ __forceinline__ unsigned short f2bf_rne(float f) {
  unsigned u = __float_as_uint(f);
  unsigned r = u + 0x7FFFu + ((u >> 16) & 1u);
  return (unsigned short)(r >> 16);
}

__global__ __launch_bounds__(256)
void prep_sq(const float* __restrict__ X, const float* __restrict__ Y,
             float* __restrict__ xsq, float* __restrict__ ysq, int n) {
  int t = blockIdx.x * 256 + threadIdx.x;
  int row = t >> 4;       // 16 lanes per row
  int c = t & 15;
  const float* src;
  float* dst;
  if (row < n) { src = X + (long)row * DD; dst = xsq + row; }
  else         { src = Y + (long)(row - n) * DD; dst = ysq + (row - n); }
  float4 v = ((const float4*)src)[c];
  float s = v.x * v.x + v.y * v.y + v.z * v.z + v.w * v.w;
  s += __shfl_xor(s, 1);
  s += __shfl_xor(s, 2);
  s += __shfl_xor(s, 4);
  s += __shfl_xor(s, 8);
  if (c == 0) *dst = s;
}

__global__ __launch_bounds__(256, 2)
void rbf_mfma(const float* __restrict__ X, const float* __restrict__ Y,
              const float* __restrict__ gptr,
              const float* __restrict__ xsq, const float* __restrict__ ysq,
              float* __restrict__ Out, int mcols) {
  // 4 tiles of 128 rows x 64 bf16 (128 B/row), XOR-swizzled. 64 KB total.
  __shared__ unsigned short XH[BM * DD], XL[BM * DD];
  __shared__ unsigned short YH[BN * DD], YL[BN * DD];

  const int tid = threadIdx.x;
  const long i0 = (long)blockIdx.y * BM;
  const long j0 = (long)blockIdx.x * BN;

  // ---- stage + hi/lo split: 4096 chunks of 4 floats (X: e<2048, Y: rest)
#pragma unroll
  for (int it = 0; it < 16; ++it) {
    int e = it * 256 + tid;
    int half = e >> 11;              // 0: X, 1: Y (uniform per iteration)
    int idx = e & 2047;
    int row = idx >> 4;              // 0..127
    int c4 = idx & 15;               // float4 index within row
    const float* src = half ? (Y + (j0 + row) * DD) : (X + (i0 + row) * DD);
    float4 v = ((const float4*)src)[c4];
    float f[4] = {v.x, v.y, v.z, v.w};
    unsigned short h[4], l[4];
#pragma unroll
    for (int q = 0; q < 4; ++q) {
      h[q] = f2bf_rne(f[q]);
      float hv = __uint_as_float(((unsigned)h[q]) << 16);
      l[q] = f2bf_rne(f[q] - hv);
    }
    int sw = (c4 * 8) ^ ((row & 7) << 4);   // swizzled byte offset in row
    unsigned short* Ht = half ? YH : XH;
    unsigned short* Lt = half ? YL : XL;
    *(ushort4*)((char*)Ht + row * 128 + sw) = make_ushort4(h[0], h[1], h[2], h[3]);
    *(ushort4*)((char*)Lt + row * 128 + sw) = make_ushort4(l[0], l[1], l[2], l[3]);
  }
  __syncthreads();

  // ---- MFMA: 3 passes (hi*hi, lo*hi, hi*lo), 2 k-steps of 32 each
  const int lane = tid & 63;
  const int wid = tid >> 6;        // 0..3
  const int wr = wid >> 1, wc = wid & 1;
  const int lr = lane & 15;
  const int hg = lane >> 4;        // 0..3

  f32x4 acc[4][4];
#pragma unroll
  for (int a = 0; a < 4; ++a)
#pragma unroll
    for (int b = 0; b < 4; ++b) acc[a][b] = (f32x4){0.f, 0.f, 0.f, 0.f};

  const unsigned short* At[3] = {XH, XL, XH};
  const unsigned short* Bt[3] = {YH, YH, YL};
#pragma unroll
  for (int p = 0; p < 3; ++p) {
#pragma unroll
    for (int s = 0; s < 2; ++s) {
      const int kbyte = (s * 32 + hg * 8) * 2;   // 16-aligned
      short8 af[4], bfv[4];
#pragma unroll
      for (int m2 = 0; m2 < 4; ++m2) {
        int row = wr * 64 + m2 * 16 + lr;
        af[m2] = *(const short8*)((const char*)At[p] + row * 128 + (kbyte ^ ((row & 7) << 4)));
      }
#pragma unroll
      for (int n2 = 0; n2 < 4; ++n2) {
        int row = wc * 64 + n2 * 16 + lr;
        bfv[n2] = *(const short8*)((const char*)Bt[p] + row * 128 + (kbyte ^ ((row & 7) << 4)));
      }
#pragma unroll
      for (int m2 = 0; m2 < 4; ++m2)
#pragma unroll
        for (int n2 = 0; n2 < 4; ++n2)
          acc[m2][n2] = __builtin_amdgcn_mfma_f32_16x16x32_bf16(af[m2], bfv[n2], acc[m2][n2], 0, 0, 0);
    }
  }

  // ---- epilogue: exp(-g * max(x2 + y2 - 2xy, 0))
  const float g = *gptr;
  float yv[4];
#pragma unroll
  for (int n2 = 0; n2 < 4; ++n2) yv[n2] = ysq[j0 + wc * 64 + n2 * 16 + lr];
#pragma unroll
  for (int m2 = 0; m2 < 4; ++m2) {
#pragma unroll
    for (int j = 0; j < 4; ++j) {
      long row = i0 + wr * 64 + m2 * 16 + hg * 4 + j;
      float xr = xsq[row];
      float* op = Out + row * (long)mcols + j0 + wc * 64 + lr;
#pragma unroll
      for (int n2 = 0; n2 < 4; ++n2) {
        float d = fmaxf(xr + yv[n2] - 2.0f * acc[m2][n2][j], 0.f);
        op[n2 * 16] = __expf(-g * d);
      }
    }
  }
}

extern "C" void kernel_launch(void* const* d_in, const int* in_sizes, int n_in,
                              void* d_out, int out_size, void* d_ws, size_t ws_size,
                              hipStream_t stream) {
  const float* x = (const float*)d_in[0];
  const float* y = (const float*)d_in[1];
  const float* g = (const float*)d_in[2];
  float* out = (float*)d_out;

  const int n = in_sizes[0] / DD;   // 8192
  const int m = in_sizes[1] / DD;   // 8192

  float* xsq = (float*)d_ws;        // n floats
  float* ysq = xsq + n;             // m floats (64 KB total in ws)

  prep_sq<<<(n + m) / 16, 256, 0, stream>>>(x, y, xsq, ysq, n);

  dim3 grid(m / BN, n / BM);        // 64 x 64 = 4096 blocks
  rbf_mfma<<<grid, 256, 0, stream>>>(x, y, g, xsq, ysq, out, m);
}

// Round 3
// 60.929 us; speedup vs baseline: 61.8402x; 1.0086x over previous
//
#include <hip/hip_runtime.h>
#include <hip/hip_bf16.h>

// RBF kernel matrix: out[i][j] = exp(-gamma * max(x2[i] + y2[j] - 2*x.y, 0))
//
// Round 3: pre-split bf16 hi/lo in a prep kernel (into d_ws, pre-swizzled row
// images) -> GEMM tiles staged via global_load_lds width-16 DMA (no per-block
// conversion VALU). MFMA operand order swapped so each lane's 4 accumulator
// regs are 4 consecutive output COLUMNS -> float4 stores. Epilogue folds
// -gamma*log2(e) into pre-scaled norms: per element add + fma + fmin + v_exp.
// 3 passes (hi*hi + lo*hi + hi*lo), drop lo*lo (~1e-21 abs output error).
// Write-bound target: 268 MB out @ ~7.1 TB/s achievable => ~38 us floor.
// Fallback to the proven round-2 kernel if ws_size is too small.

#define DD 64
#define BM 128
#define BN 128

typedef __attribute__((ext_vector_type(8))) short short8;
typedef __attribute__((ext_vector_type(4))) float f32x4;

#if __has_builtin(__builtin_amdgcn_exp2f)
#define EXP2(x) __builtin_amdgcn_exp2f(x)
#else
#define EXP2(x) exp2f(x)
#endif

__device__ __forceinline__ unsigned short f2bf_rne(float f) {
  unsigned u = __float_as_uint(f);
  unsigned r = u + 0x7FFFu + ((u >> 16) & 1u);
  return (unsigned short)(r >> 16);
}

// ---------------- prep: fp32 norms + bf16 hi/lo pre-split (pre-swizzled) ----
__global__ __launch_bounds__(256)
void prep_split(const float* __restrict__ X, const float* __restrict__ Y,
                unsigned short* __restrict__ XHg, unsigned short* __restrict__ XLg,
                unsigned short* __restrict__ YHg, unsigned short* __restrict__ YLg,
                float* __restrict__ xsq, float* __restrict__ ysq, int n) {
  int t = blockIdx.x * 256 + threadIdx.x;
  int row = t >> 4;       // 16 lanes per row
  int c4 = t & 15;        // float4 index within row
  const float* src;
  unsigned short *hd, *ld;
  float* nd;
  int r;
  if (row < n) { r = row;     src = X + (long)r * DD; hd = XHg; ld = XLg; nd = xsq + r; }
  else         { r = row - n; src = Y + (long)r * DD; hd = YHg; ld = YLg; nd = ysq + r; }
  float4 v = ((const float4*)src)[c4];
  float f[4] = {v.x, v.y, v.z, v.w};
  unsigned short h[4], l[4];
#pragma unroll
  for (int q = 0; q < 4; ++q) {
    h[q] = f2bf_rne(f[q]);
    float hv = __uint_as_float(((unsigned)h[q]) << 16);
    l[q] = f2bf_rne(f[q] - hv);
  }
  int sw = (c4 * 8) ^ ((r & 7) << 4);   // swizzled byte offset within 128-B row
  *(ushort4*)((char*)hd + (long)r * 128 + sw) = make_ushort4(h[0], h[1], h[2], h[3]);
  *(ushort4*)((char*)ld + (long)r * 128 + sw) = make_ushort4(l[0], l[1], l[2], l[3]);
  float s = v.x * v.x + v.y * v.y + v.z * v.z + v.w * v.w;
  s += __shfl_xor(s, 1);
  s += __shfl_xor(s, 2);
  s += __shfl_xor(s, 4);
  s += __shfl_xor(s, 8);
  if (c4 == 0) *nd = s;
}

// ---------------- main: DMA-staged MFMA GEMM + fused exp epilogue ----------
__global__ __launch_bounds__(256, 2)
void rbf_mfma_dma(const unsigned short* __restrict__ XHg, const unsigned short* __restrict__ XLg,
                  const unsigned short* __restrict__ YHg, const unsigned short* __restrict__ YLg,
                  const float* __restrict__ gptr,
                  const float* __restrict__ xsq, const float* __restrict__ ysq,
                  float* __restrict__ Out, int mcols) {
  // 4 tiles of 128 rows x 128 B (swizzled image), 16 KB each = 64 KB.
  __shared__ __align__(128) char lds[65536];

  const int tid = threadIdx.x;
  const int lane = tid & 63;
  const int wid = tid >> 6;        // 0..3
  const long i0 = (long)blockIdx.y * BM;
  const long j0 = (long)blockIdx.x * BN;

  // ---- stage: 4 contiguous 16-KB slices, global_load_lds width 16
  const char* srcs[4] = {(const char*)XHg + i0 * 128, (const char*)XLg + i0 * 128,
                         (const char*)YHg + j0 * 128, (const char*)YLg + j0 * 128};
#pragma unroll
  for (int t4 = 0; t4 < 4; ++t4) {
#pragma unroll
    for (int it = 0; it < 4; ++it) {
      int off = it * 4096 + wid * 1024;           // wave-uniform
      const char* g = srcs[t4] + off + lane * 16; // per-lane global src
      __builtin_amdgcn_global_load_lds(
          (const __attribute__((address_space(1))) void*)g,
          (__attribute__((address_space(3))) void*)(lds + t4 * 16384 + off),
          16, 0, 0);
    }
  }
  __syncthreads();   // compiler drains vmcnt before the barrier

  // ---- MFMA: 3 passes (hi*hi, lo*hi, hi*lo), 2 k-steps of 32 each
  const int wr = wid >> 1, wc = wid & 1;
  const int lr = lane & 15;
  const int hg = lane >> 4;        // 0..3

  f32x4 acc[4][4];
#pragma unroll
  for (int a = 0; a < 4; ++a)
#pragma unroll
    for (int b = 0; b < 4; ++b) acc[a][b] = (f32x4){0.f, 0.f, 0.f, 0.f};

  const char* At[3] = {lds, lds + 16384, lds};             // XH, XL, XH
  const char* Bt[3] = {lds + 32768, lds + 32768, lds + 49152}; // YH, YH, YL
#pragma unroll
  for (int p = 0; p < 3; ++p) {
#pragma unroll
    for (int s = 0; s < 2; ++s) {
      const int kbyte = s * 64 + hg * 16;
      short8 af[4], bfv[4];
#pragma unroll
      for (int m2 = 0; m2 < 4; ++m2) {
        int row = wr * 64 + m2 * 16 + lr;
        af[m2] = *(const short8*)(At[p] + row * 128 + (kbyte ^ ((row & 7) << 4)));
      }
#pragma unroll
      for (int n2 = 0; n2 < 4; ++n2) {
        int row = wc * 64 + n2 * 16 + lr;
        bfv[n2] = *(const short8*)(Bt[p] + row * 128 + (kbyte ^ ((row & 7) << 4)));
      }
      // Swapped operands: reg dim = Y rows (output cols), lane&15 = X rows.
#pragma unroll
      for (int m2 = 0; m2 < 4; ++m2)
#pragma unroll
        for (int n2 = 0; n2 < 4; ++n2)
          acc[m2][n2] = __builtin_amdgcn_mfma_f32_16x16x32_bf16(bfv[n2], af[m2], acc[m2][n2], 0, 0, 0);
    }
  }

  // ---- epilogue: out = 2^( min( c*x2 + c*y2 + 2|c|*xy, 0 ) ), c = -g*log2e
  const float g = *gptr;
  const float cf = -g * 1.4426950408889634f;
  const float nc2 = -2.0f * cf;
  float cxr[4];
#pragma unroll
  for (int m2 = 0; m2 < 4; ++m2) cxr[m2] = cf * xsq[i0 + wr * 64 + m2 * 16 + lr];
  float4 cyv[4];
#pragma unroll
  for (int n2 = 0; n2 < 4; ++n2) {
    float4 yq = *(const float4*)&ysq[j0 + wc * 64 + n2 * 16 + hg * 4];
    cyv[n2] = make_float4(cf * yq.x, cf * yq.y, cf * yq.z, cf * yq.w);
  }
#pragma unroll
  for (int m2 = 0; m2 < 4; ++m2) {
    long row = i0 + wr * 64 + m2 * 16 + lr;
    float* op = Out + row * (long)mcols + j0 + wc * 64 + hg * 4;
#pragma unroll
    for (int n2 = 0; n2 < 4; ++n2) {
      float cy[4] = {cyv[n2].x, cyv[n2].y, cyv[n2].z, cyv[n2].w};
      float o[4];
#pragma unroll
      for (int j = 0; j < 4; ++j)
        o[j] = EXP2(fminf(fmaf(nc2, acc[m2][n2][j], cxr[m2] + cy[j]), 0.f));
      *(float4*)(op + n2 * 16) = *(float4*)o;
    }
  }
}

// ---------------- fallback (proven round-2 path) ---------------------------
__global__ __launch_bounds__(256)
void prep_sq(const float* __restrict__ X, const float* __restrict__ Y,
             float* __restrict__ xsq, float* __restrict__ ysq, int n) {
  int t = blockIdx.x * 256 + threadIdx.x;
  int row = t >> 4;
  int c = t & 15;
  const float* src;
  float* dst;
  if (row < n) { src = X + (long)row * DD; dst = xsq + row; }
  else         { src = Y + (long)(row - n) * DD; dst = ysq + (row - n); }
  float4 v = ((const float4*)src)[c];
  float s = v.x * v.x + v.y * v.y + v.z * v.z + v.w * v.w;
  s += __shfl_xor(s, 1);
  s += __shfl_xor(s, 2);
  s += __shfl_xor(s, 4);
  s += __shfl_xor(s, 8);
  if (c == 0) *dst = s;
}

__global__ __launch_bounds__(256, 2)
void rbf_mfma_fb(const float* __restrict__ X, const float* __restrict__ Y,
                 const float* __restrict__ gptr,
                 const float* __restrict__ xsq, const float* __restrict__ ysq,
                 float* __restrict__ Out, int mcols) {
  __shared__ unsigned short XH[BM * DD], XL[BM * DD];
  __shared__ unsigned short YH[BN * DD], YL[BN * DD];
  const int tid = threadIdx.x;
  const long i0 = (long)blockIdx.y * BM;
  const long j0 = (long)blockIdx.x * BN;
#pragma unroll
  for (int it = 0; it < 16; ++it) {
    int e = it * 256 + tid;
    int half = e >> 11;
    int idx = e & 2047;
    int row = idx >> 4;
    int c4 = idx & 15;
    const float* src = half ? (Y + (j0 + row) * DD) : (X + (i0 + row) * DD);
    float4 v = ((const float4*)src)[c4];
    float f[4] = {v.x, v.y, v.z, v.w};
    unsigned short h[4], l[4];
#pragma unroll
    for (int q = 0; q < 4; ++q) {
      h[q] = f2bf_rne(f[q]);
      float hv = __uint_as_float(((unsigned)h[q]) << 16);
      l[q] = f2bf_rne(f[q] - hv);
    }
    int sw = (c4 * 8) ^ ((row & 7) << 4);
    unsigned short* Ht = half ? YH : XH;
    unsigned short* Lt = half ? YL : XL;
    *(ushort4*)((char*)Ht + row * 128 + sw) = make_ushort4(h[0], h[1], h[2], h[3]);
    *(ushort4*)((char*)Lt + row * 128 + sw) = make_ushort4(l[0], l[1], l[2], l[3]);
  }
  __syncthreads();
  const int lane = tid & 63;
  const int wid = tid >> 6;
  const int wr = wid >> 1, wc = wid & 1;
  const int lr = lane & 15;
  const int hg = lane >> 4;
  f32x4 acc[4][4];
#pragma unroll
  for (int a = 0; a < 4; ++a)
#pragma unroll
    for (int b = 0; b < 4; ++b) acc[a][b] = (f32x4){0.f, 0.f, 0.f, 0.f};
  const unsigned short* At[3] = {XH, XL, XH};
  const unsigned short* Bt[3] = {YH, YH, YL};
#pragma unroll
  for (int p = 0; p < 3; ++p) {
#pragma unroll
    for (int s = 0; s < 2; ++s) {
      const int kbyte = s * 64 + hg * 16;
      short8 af[4], bfv[4];
#pragma unroll
      for (int m2 = 0; m2 < 4; ++m2) {
        int row = wr * 64 + m2 * 16 + lr;
        af[m2] = *(const short8*)((const char*)At[p] + row * 128 + (kbyte ^ ((row & 7) << 4)));
      }
#pragma unroll
      for (int n2 = 0; n2 < 4; ++n2) {
        int row = wc * 64 + n2 * 16 + lr;
        bfv[n2] = *(const short8*)((const char*)Bt[p] + row * 128 + (kbyte ^ ((row & 7) << 4)));
      }
#pragma unroll
      for (int m2 = 0; m2 < 4; ++m2)
#pragma unroll
        for (int n2 = 0; n2 < 4; ++n2)
          acc[m2][n2] = __builtin_amdgcn_mfma_f32_16x16x32_bf16(af[m2], bfv[n2], acc[m2][n2], 0, 0, 0);
    }
  }
  const float g = *gptr;
  float yv[4];
#pragma unroll
  for (int n2 = 0; n2 < 4; ++n2) yv[n2] = ysq[j0 + wc * 64 + n2 * 16 + lr];
#pragma unroll
  for (int m2 = 0; m2 < 4; ++m2) {
#pragma unroll
    for (int j = 0; j < 4; ++j) {
      long row = i0 + wr * 64 + m2 * 16 + hg * 4 + j;
      float xr = xsq[row];
      float* op = Out + row * (long)mcols + j0 + wc * 64 + lr;
#pragma unroll
      for (int n2 = 0; n2 < 4; ++n2) {
        float d = fmaxf(xr + yv[n2] - 2.0f * acc[m2][n2][j], 0.f);
        op[n2 * 16] = __expf(-g * d);
      }
    }
  }
}

extern "C" void kernel_launch(void* const* d_in, const int* in_sizes, int n_in,
                              void* d_out, int out_size, void* d_ws, size_t ws_size,
                              hipStream_t stream) {
  const float* x = (const float*)d_in[0];
  const float* y = (const float*)d_in[1];
  const float* g = (const float*)d_in[2];
  float* out = (float*)d_out;

  const int n = in_sizes[0] / DD;   // 8192
  const int m = in_sizes[1] / DD;   // 8192

  const size_t split_bytes = (size_t)(n + m) * DD * 2 * sizeof(unsigned short);
  const size_t needed = split_bytes + (size_t)(n + m) * sizeof(float);

  dim3 grid(m / BN, n / BM);        // 64 x 64 = 4096 blocks

  if (ws_size >= needed) {
    unsigned short* XHg = (unsigned short*)d_ws;
    unsigned short* XLg = XHg + (size_t)n * DD;
    unsigned short* YHg = XLg + (size_t)n * DD;
    unsigned short* YLg = YHg + (size_t)m * DD;
    float* xsq = (float*)(YLg + (size_t)m * DD);
    float* ysq = xsq + n;
    prep_split<<<(n + m) / 16, 256, 0, stream>>>(x, y, XHg, XLg, YHg, YLg, xsq, ysq, n);
    rbf_mfma_dma<<<grid, 256, 0, stream>>>(XHg, XLg, YHg, YLg, g, xsq, ysq, out, m);
  } else {
    float* xsq = (float*)d_ws;
    float* ysq = xsq + n;
    prep_sq<<<(n + m) / 16, 256, 0, stream>>>(x, y, xsq, ysq, n);
    rbf_mfma_fb<<<grid, 256, 0, stream>>>(x, y, g, xsq, ysq, out, m);
  }
}